// Round 2
// baseline (168.236 us; speedup 1.0000x reference)
//
#include <hip/hip_runtime.h>
#include <hip/hip_fp16.h>
#include <math.h>

#define N_NODES 100000
#define N_HID 128
#define E_PER_REL 200000
#define THREADS 256

// ---- main kernel geometry: 16 lanes per edge, 4 edges per group ----
#define EDGES 4
#define GROUPS (E_PER_REL / EDGES)            // 50000 groups per relation

// ---- fallback geometry (old 8-lane kernel) ----
#define EDGES_PER_GROUP 2
#define GROUPS_PER_REL (E_PER_REL / EDGES_PER_GROUP)

// ---------------- pass 1: h (fp32) -> h16 (fp16) in workspace ----------------
// Fully coalesced: each thread does one 16B float4 load and one 8B half4
// store, both contiguous across lanes within each instruction.
__global__ __launch_bounds__(THREADS) void convert_h_kernel(
    const float* __restrict__ h, __half* __restrict__ h16, int n4)
{
    int i = blockIdx.x * blockDim.x + threadIdx.x;
    if (i >= n4) return;
    float4 a = reinterpret_cast<const float4*>(h)[i];
    __half2 r0 = __floats2half2_rn(a.x, a.y);
    __half2 r1 = __floats2half2_rn(a.z, a.w);
    float2 packed;
    *reinterpret_cast<__half2*>(&packed.x) = r0;
    *reinterpret_cast<__half2*>(&packed.y) = r1;
    reinterpret_cast<float2*>(h16)[i] = packed;
}

// ---------------- pass 2: gather h16 rows, dot, sigmoid ----------------------
// 16 lanes per edge: each lane covers 8 dims = ONE 16B load per row, so a
// full row is a single wave-coherent 256B contiguous burst (4 cache lines).
// 4 edges per group, ALL index loads and ALL 8 gather loads issued before
// any waitcnt -> ~128 cache lines in flight per wave (vs ~64 before).
// The kernel is latency-bound on the random L2-miss path (R1: 73us at
// 3.6 TB/s fetch, well under both L2 and L3 BW floors), so deeper per-wave
// MLP is the lever. VGPR pinned <=64 via launch_bounds(256,8) to keep
// 8 waves/SIMD occupancy.
__global__ __launch_bounds__(THREADS, 8) void distmult_fp16_kernel(
    const __half* __restrict__ h16,
    const float* __restrict__ W,
    const int* __restrict__ src_idx,
    const int* __restrict__ dst_idx,
    float* __restrict__ out)
{
    const int lane16 = threadIdx.x & 15;
    const int group  = (blockIdx.x * THREADS + threadIdx.x) >> 4;  // 0..GROUPS-1
    const int rel    = blockIdx.y;

    const int ebase = rel * E_PER_REL + group;

    // ---- issue all 8 index loads (streamed once: nontemporal) ----
    int s[EDGES], d[EDGES];
    #pragma unroll
    for (int k = 0; k < EDGES; ++k) {
        s[k] = __builtin_nontemporal_load(src_idx + ebase + k * GROUPS);
        d[k] = __builtin_nontemporal_load(dst_idx + ebase + k * GROUPS);
    }

    // ---- issue all 8 row gathers (16B per lane, one instr per row) ----
    float4 u[EDGES], v[EDGES];
    #pragma unroll
    for (int k = 0; k < EDGES; ++k) {
        const float4* hu = (const float4*)(h16 + s[k] * N_HID);
        const float4* hv = (const float4*)(h16 + d[k] * N_HID);
        u[k] = hu[lane16];
        v[k] = hv[lane16];
    }

    // ---- W chunk for this lane (L1/L2-hot, loaded after gathers are in
    //      flight to reduce peak register pressure during the issue window)
    const float4* wr4 = (const float4*)(W + rel * N_HID);
    const float4 w0 = wr4[2 * lane16];       // dims 8*lane16 .. +4
    const float4 w1 = wr4[2 * lane16 + 1];   // dims 8*lane16+4 .. +8

    #pragma unroll
    for (int k = 0; k < EDGES; ++k) {
        const __half2* uu = (const __half2*)&u[k];
        const __half2* vv = (const __half2*)&v[k];

        float2 ua, va;
        float acc;
        ua = __half22float2(uu[0]); va = __half22float2(vv[0]);
        acc  = ua.x * va.x * w0.x + ua.y * va.y * w0.y;
        ua = __half22float2(uu[1]); va = __half22float2(vv[1]);
        acc += ua.x * va.x * w0.z + ua.y * va.y * w0.w;
        ua = __half22float2(uu[2]); va = __half22float2(vv[2]);
        acc += ua.x * va.x * w1.x + ua.y * va.y * w1.y;
        ua = __half22float2(uu[3]); va = __half22float2(vv[3]);
        acc += ua.x * va.x * w1.z + ua.y * va.y * w1.w;

        // reduce across the 16-lane group
        acc += __shfl_xor(acc, 1);
        acc += __shfl_xor(acc, 2);
        acc += __shfl_xor(acc, 4);
        acc += __shfl_xor(acc, 8);

        if (lane16 == 0) {
            float sig = 1.0f / (1.0f + __expf(-acc));
            __builtin_nontemporal_store(sig, out + ebase + k * GROUPS);
        }
    }
}

// ---------------- fallback: fp32 gather (R2 kernel) --------------------------
__global__ __launch_bounds__(THREADS) void distmult_fp32_kernel(
    const float* __restrict__ h,
    const float* __restrict__ W,
    const int* __restrict__ src_idx,
    const int* __restrict__ dst_idx,
    float* __restrict__ out)
{
    const int lane8 = threadIdx.x & 7;
    const int group = (blockIdx.x * THREADS + threadIdx.x) >> 3;
    const int rel   = blockIdx.y;

    const float4* wr = (const float4*)(W + rel * N_HID);
    const float4 w0 = wr[lane8];
    const float4 w1 = wr[lane8 + 8];
    const float4 w2 = wr[lane8 + 16];
    const float4 w3 = wr[lane8 + 24];

    int e = rel * E_PER_REL + group;

    #pragma unroll
    for (int k = 0; k < EDGES_PER_GROUP; ++k, e += GROUPS_PER_REL) {
        const int s = src_idx[e];
        const int d = dst_idx[e];
        const float4* hu = (const float4*)(h + (size_t)s * N_HID);
        const float4* hv = (const float4*)(h + (size_t)d * N_HID);
        const float4 u0 = hu[lane8],      v0 = hv[lane8];
        const float4 u1 = hu[lane8 + 8],  v1 = hv[lane8 + 8];
        const float4 u2 = hu[lane8 + 16], v2 = hv[lane8 + 16];
        const float4 u3 = hu[lane8 + 24], v3 = hv[lane8 + 24];

        float p;
        p  = (u0.x * v0.x) * w0.x + (u0.y * v0.y) * w0.y + (u0.z * v0.z) * w0.z + (u0.w * v0.w) * w0.w;
        p += (u1.x * v1.x) * w1.x + (u1.y * v1.y) * w1.y + (u1.z * v1.z) * w1.z + (u1.w * v1.w) * w1.w;
        p += (u2.x * v2.x) * w2.x + (u2.y * v2.y) * w2.y + (u2.z * v2.z) * w2.z + (u2.w * v2.w) * w2.w;
        p += (u3.x * v3.x) * w3.x + (u3.y * v3.y) * w3.y + (u3.z * v3.z) * w3.z + (u3.w * v3.w) * w3.w;

        p += __shfl_xor(p, 1);
        p += __shfl_xor(p, 2);
        p += __shfl_xor(p, 4);

        if (lane8 == 0) out[e] = 1.0f / (1.0f + __expf(-p));
    }
}

extern "C" void kernel_launch(void* const* d_in, const int* in_sizes, int n_in,
                              void* d_out, int out_size, void* d_ws, size_t ws_size,
                              hipStream_t stream) {
    const float* h       = (const float*)d_in[0];
    const float* W       = (const float*)d_in[1];
    const int*   src_idx = (const int*)d_in[2];
    const int*   dst_idx = (const int*)d_in[3];
    float*       out     = (float*)d_out;

    const size_t need = (size_t)N_NODES * N_HID * sizeof(__half);  // 25.6 MB

    if (ws_size >= need) {
        __half* h16 = (__half*)d_ws;
        const int n4 = N_NODES * N_HID / 4;  // 3.2M threads, 16B->8B each
        convert_h_kernel<<<(n4 + THREADS - 1) / THREADS, THREADS, 0, stream>>>(h, h16, n4);
        dim3 grid(GROUPS * 16 / THREADS, 6, 1);   // 3125 x 6
        distmult_fp16_kernel<<<grid, THREADS, 0, stream>>>(h16, W, src_idx, dst_idx, out);
    } else {
        dim3 grid(GROUPS_PER_REL * 8 / THREADS, 6, 1);
        distmult_fp32_kernel<<<grid, THREADS, 0, stream>>>(h, W, src_idx, dst_idx, out);
    }
}

// Round 3
// 166.223 us; speedup vs baseline: 1.0121x; 1.0121x over previous
//
#include <hip/hip_runtime.h>
#include <hip/hip_fp16.h>
#include <math.h>

#define N_NODES 100000
#define N_HID 128
#define E_PER_REL 200000
#define EDGES_PER_GROUP 2
#define GROUPS_PER_REL (E_PER_REL / EDGES_PER_GROUP)   // 100000
#define THREADS 256

// ---------------- pass 1: h (fp32) -> h16 (fp16) in workspace ----------------
// Fully coalesced: each thread does one 16B float4 load and one 8B half4
// store, both contiguous across lanes within each instruction.
__global__ __launch_bounds__(THREADS) void convert_h_kernel(
    const float* __restrict__ h, __half* __restrict__ h16, int n4)
{
    int i = blockIdx.x * blockDim.x + threadIdx.x;
    if (i >= n4) return;
    float4 a = reinterpret_cast<const float4*>(h)[i];
    __half2 r0 = __floats2half2_rn(a.x, a.y);
    __half2 r1 = __floats2half2_rn(a.z, a.w);
    float2 packed;
    *reinterpret_cast<__half2*>(&packed.x) = r0;
    *reinterpret_cast<__half2*>(&packed.y) = r1;
    reinterpret_cast<float2*>(h16)[i] = packed;
}

// ---------------- pass 2: gather h16 rows (256B), dot, sigmoid ---------------
// R1 geometry (measured 73.2us): 8 lanes/edge, 2 edges/group, plain
// loads/stores. R3 change: ALL 4 idx loads then ALL 8 row gathers are
// issued before a sched_barrier(0), so the compiler cannot sink loads
// to their uses (R2 post-mortem: VGPR=28 proved it was serializing the
// gathers; the MLP experiment never ran). Payload alone needs 32 VGPRs;
// expect ~48-64 total. No waves/EU pin -> no spill pressure.
__global__ __launch_bounds__(THREADS) void distmult_fp16_kernel(
    const __half* __restrict__ h16,
    const float* __restrict__ W,
    const int* __restrict__ src_idx,
    const int* __restrict__ dst_idx,
    float* __restrict__ out)
{
    const int lane8 = threadIdx.x & 7;
    const int group = (blockIdx.x * THREADS + threadIdx.x) >> 3;  // 0..GROUPS_PER_REL-1
    const int rel   = blockIdx.y;

    // W: lane8 covers dims [8*lane8, +8) and [64+8*lane8, +8); L1/L2-hot.
    const float4* wr4 = (const float4*)(W + rel * N_HID);
    const float4 wa0 = wr4[2 * lane8];
    const float4 wa1 = wr4[2 * lane8 + 1];
    const float4 wb0 = wr4[16 + 2 * lane8];
    const float4 wb1 = wr4[16 + 2 * lane8 + 1];

    const float wlo[8] = {wa0.x, wa0.y, wa0.z, wa0.w, wa1.x, wa1.y, wa1.z, wa1.w};
    const float whi[8] = {wb0.x, wb0.y, wb0.z, wb0.w, wb1.x, wb1.y, wb1.z, wb1.w};

    const int e0 = rel * E_PER_REL + group;
    const int e1 = e0 + GROUPS_PER_REL;

    // ---- issue all index loads ----
    const int s0 = src_idx[e0];
    const int d0 = dst_idx[e0];
    const int s1 = src_idx[e1];
    const int d1 = dst_idx[e1];

    // ---- issue all 8 row gathers before any use ----
    const float4* hu0 = (const float4*)(h16 + (size_t)s0 * N_HID);
    const float4* hv0 = (const float4*)(h16 + (size_t)d0 * N_HID);
    const float4* hu1 = (const float4*)(h16 + (size_t)s1 * N_HID);
    const float4* hv1 = (const float4*)(h16 + (size_t)d1 * N_HID);

    float4 u00 = hu0[lane8];      // edge0 src, dims lo
    float4 u01 = hu0[lane8 + 8];  // edge0 src, dims hi
    float4 v00 = hv0[lane8];
    float4 v01 = hv0[lane8 + 8];
    float4 u10 = hu1[lane8];      // edge1 src
    float4 u11 = hu1[lane8 + 8];
    float4 v10 = hv1[lane8];
    float4 v11 = hv1[lane8 + 8];

    // Keep the 8 loads clustered above the compute: no reordering across.
    __builtin_amdgcn_sched_barrier(0);

    // ---- edge 0 ----
    {
        const __half2* u0 = (const __half2*)&u00;
        const __half2* u1 = (const __half2*)&u01;
        const __half2* v0 = (const __half2*)&v00;
        const __half2* v1 = (const __half2*)&v01;
        float p = 0.0f;
        #pragma unroll
        for (int j = 0; j < 4; ++j) {
            float2 uu = __half22float2(u0[j]);
            float2 vv = __half22float2(v0[j]);
            p += uu.x * vv.x * wlo[2 * j];
            p += uu.y * vv.y * wlo[2 * j + 1];
        }
        #pragma unroll
        for (int j = 0; j < 4; ++j) {
            float2 uu = __half22float2(u1[j]);
            float2 vv = __half22float2(v1[j]);
            p += uu.x * vv.x * whi[2 * j];
            p += uu.y * vv.y * whi[2 * j + 1];
        }
        p += __shfl_xor(p, 1);
        p += __shfl_xor(p, 2);
        p += __shfl_xor(p, 4);
        if (lane8 == 0) out[e0] = 1.0f / (1.0f + __expf(-p));
    }

    // ---- edge 1 ----
    {
        const __half2* u0 = (const __half2*)&u10;
        const __half2* u1 = (const __half2*)&u11;
        const __half2* v0 = (const __half2*)&v10;
        const __half2* v1 = (const __half2*)&v11;
        float p = 0.0f;
        #pragma unroll
        for (int j = 0; j < 4; ++j) {
            float2 uu = __half22float2(u0[j]);
            float2 vv = __half22float2(v0[j]);
            p += uu.x * vv.x * wlo[2 * j];
            p += uu.y * vv.y * wlo[2 * j + 1];
        }
        #pragma unroll
        for (int j = 0; j < 4; ++j) {
            float2 uu = __half22float2(u1[j]);
            float2 vv = __half22float2(v1[j]);
            p += uu.x * vv.x * whi[2 * j];
            p += uu.y * vv.y * whi[2 * j + 1];
        }
        p += __shfl_xor(p, 1);
        p += __shfl_xor(p, 2);
        p += __shfl_xor(p, 4);
        if (lane8 == 0) out[e1] = 1.0f / (1.0f + __expf(-p));
    }
}

// ---------------- fallback: fp32 gather (R2 kernel) --------------------------
__global__ __launch_bounds__(THREADS) void distmult_fp32_kernel(
    const float* __restrict__ h,
    const float* __restrict__ W,
    const int* __restrict__ src_idx,
    const int* __restrict__ dst_idx,
    float* __restrict__ out)
{
    const int lane8 = threadIdx.x & 7;
    const int group = (blockIdx.x * THREADS + threadIdx.x) >> 3;
    const int rel   = blockIdx.y;

    const float4* wr = (const float4*)(W + rel * N_HID);
    const float4 w0 = wr[lane8];
    const float4 w1 = wr[lane8 + 8];
    const float4 w2 = wr[lane8 + 16];
    const float4 w3 = wr[lane8 + 24];

    int e = rel * E_PER_REL + group;

    #pragma unroll
    for (int k = 0; k < EDGES_PER_GROUP; ++k, e += GROUPS_PER_REL) {
        const int s = src_idx[e];
        const int d = dst_idx[e];
        const float4* hu = (const float4*)(h + (size_t)s * N_HID);
        const float4* hv = (const float4*)(h + (size_t)d * N_HID);
        const float4 u0 = hu[lane8],      v0 = hv[lane8];
        const float4 u1 = hu[lane8 + 8],  v1 = hv[lane8 + 8];
        const float4 u2 = hu[lane8 + 16], v2 = hv[lane8 + 16];
        const float4 u3 = hu[lane8 + 24], v3 = hv[lane8 + 24];

        float p;
        p  = (u0.x * v0.x) * w0.x + (u0.y * v0.y) * w0.y + (u0.z * v0.z) * w0.z + (u0.w * v0.w) * w0.w;
        p += (u1.x * v1.x) * w1.x + (u1.y * v1.y) * w1.y + (u1.z * v1.z) * w1.z + (u1.w * v1.w) * w1.w;
        p += (u2.x * v2.x) * w2.x + (u2.y * v2.y) * w2.y + (u2.z * v2.z) * w2.z + (u2.w * v2.w) * w2.w;
        p += (u3.x * v3.x) * w3.x + (u3.y * v3.y) * w3.y + (u3.z * v3.z) * w3.z + (u3.w * v3.w) * w3.w;

        p += __shfl_xor(p, 1);
        p += __shfl_xor(p, 2);
        p += __shfl_xor(p, 4);

        if (lane8 == 0) out[e] = 1.0f / (1.0f + __expf(-p));
    }
}

extern "C" void kernel_launch(void* const* d_in, const int* in_sizes, int n_in,
                              void* d_out, int out_size, void* d_ws, size_t ws_size,
                              hipStream_t stream) {
    const float* h       = (const float*)d_in[0];
    const float* W       = (const float*)d_in[1];
    const int*   src_idx = (const int*)d_in[2];
    const int*   dst_idx = (const int*)d_in[3];
    float*       out     = (float*)d_out;

    const size_t need = (size_t)N_NODES * N_HID * sizeof(__half);  // 25.6 MB
    dim3 grid(GROUPS_PER_REL * 8 / THREADS, 6, 1);                 // 3125 x 6

    if (ws_size >= need) {
        __half* h16 = (__half*)d_ws;
        const int n4 = N_NODES * N_HID / 4;  // 3.2M threads, 16B->8B each
        convert_h_kernel<<<(n4 + THREADS - 1) / THREADS, THREADS, 0, stream>>>(h, h16, n4);
        distmult_fp16_kernel<<<grid, THREADS, 0, stream>>>(h16, W, src_idx, dst_idx, out);
    } else {
        distmult_fp32_kernel<<<grid, THREADS, 0, stream>>>(h, W, src_idx, dst_idx, out);
    }
}